// Round 2
// baseline (208.141 us; speedup 1.0000x reference)
//
#include <hip/hip_runtime.h>

#define B_  4
#define C_  256     // C_IN == LATENT == 256
#define N_  4096    // H*W
#define SCALE 0.0625f   // 1/sqrt(256)

typedef short s8v __attribute__((ext_vector_type(8)));
typedef float f4v __attribute__((ext_vector_type(4)));

// round-to-nearest-even fp32 -> bf16 (values are finite; no NaN handling needed)
static __device__ __forceinline__ ushort f2bf(float f) {
  union { float f; uint u; } v; v.f = f;
  return (ushort)((v.u + 0x7FFFu + ((v.u >> 16) & 1u)) >> 16);
}

// async global->LDS 16B: dest is wave-uniform base + lane*16 (linear).
static __device__ __forceinline__ void gload_lds16(const ushort* g, ushort* l) {
  __builtin_amdgcn_global_load_lds(
      (const __attribute__((address_space(1))) void*)g,
      (__attribute__((address_space(3))) void*)l, 16, 0, 0);
}

// ---------------------------------------------------------------------------
// xpose_cast: x [b][c][n] fp32 -> x_t [b][n][c] bf16 + fused den zeroing.
// (R13-exact). grid (64, 4, 4).
// ---------------------------------------------------------------------------
__global__ __launch_bounds__(256) void xpose_cast(
    const float* __restrict__ x, ushort* __restrict__ x_t,
    float* __restrict__ den)
{
  const int b  = blockIdx.z;
  const int c0 = blockIdx.y * 64;
  const int n0 = blockIdx.x * 64;
  __shared__ float t[64][65];

  if (blockIdx.y == 0 && threadIdx.x < 64)
    den[b * N_ + n0 + threadIdx.x] = 0.f;

  const int tc = threadIdx.x >> 4;
  const int tn = (threadIdx.x & 15) * 4;
  #pragma unroll
  for (int cc = 0; cc < 64; cc += 16) {
    float4 v = *(const float4*)(x + (size_t)(b * C_ + c0 + cc + tc) * N_ + n0 + tn);
    t[cc + tc][tn + 0] = v.x;
    t[cc + tc][tn + 1] = v.y;
    t[cc + tc][tn + 2] = v.z;
    t[cc + tc][tn + 3] = v.w;
  }
  __syncthreads();

  const int on = threadIdx.x >> 2;
  const int oc = (threadIdx.x & 3) * 16;
  union { ushort us[16]; uint4 q[2]; } o;
  #pragma unroll
  for (int i = 0; i < 16; ++i) o.us[i] = f2bf(t[oc + i][on]);
  ushort* dst = x_t + (size_t)(b * N_ + n0 + on) * C_ + c0 + oc;
  *(uint4*)dst       = o.q[0];
  *(uint4*)(dst + 8) = o.q[1];
}

// ---------------------------------------------------------------------------
// qkv_mfma: bf16 MFMA projection (R13-exact). grid (8, 4, 12), block 256.
// ---------------------------------------------------------------------------
__global__ __launch_bounds__(256, 2) void qkv_mfma(
    const ushort* __restrict__ x_t,
    const float* __restrict__ Wq, const float* __restrict__ bq,
    const float* __restrict__ Wk, const float* __restrict__ bk,
    const float* __restrict__ Wv, const float* __restrict__ bv,
    ushort* __restrict__ q_t, ushort* __restrict__ k_t, ushort* __restrict__ v_bf)
{
  const int p = blockIdx.z >> 2;
  const int b = blockIdx.z & 3;
  const float* W  = (p == 0) ? Wq : (p == 1) ? Wk : Wv;
  const float* bi = (p == 0) ? bq : (p == 1) ? bk : bv;
  const int l0    = blockIdx.y * 64;
  const int nseg  = blockIdx.x * 512;

  const int tid  = threadIdx.x;
  const int lane = tid & 63;
  const int wave = tid >> 6;
  const int l16  = lane & 15;
  const int quad = lane >> 4;

  __shared__ __align__(16) ushort w_lds[64 * 264];
  __shared__ __align__(16) ushort x_lds[64 * 264];

  for (int g = tid; g < 4096; g += 256) {
    int row = g >> 6, col4 = (g & 63) * 4;
    float4 wv = *(const float4*)(W + (size_t)(l0 + row) * 256 + col4);
    *(ushort4*)&w_lds[row * 264 + col4] =
        make_ushort4(f2bf(wv.x), f2bf(wv.y), f2bf(wv.z), f2bf(wv.w));
  }
  __syncthreads();

  s8v kw[4][8];
  #pragma unroll
  for (int lt = 0; lt < 4; ++lt)
    #pragma unroll
    for (int cs = 0; cs < 8; ++cs)
      kw[lt][cs] = *(const s8v*)&w_lds[(lt * 16 + l16) * 264 + quad * 8 + cs * 32];

  float bias_l[4];
  #pragma unroll
  for (int lt = 0; lt < 4; ++lt) bias_l[lt] = bi[l0 + lt * 16 + l16];

  for (int it = 0; it < 8; ++it) {
    const int n0 = nseg + it * 64;
    {
      const ushort* xseg = x_t + (size_t)(b * N_ + n0) * C_;
      #pragma unroll
      for (int k = 0; k < 8; ++k) {
        int c = tid + k * 256;
        uint4 d = *(const uint4*)(xseg + (size_t)c * 8);
        *(uint4*)&x_lds[(c >> 5) * 264 + (c & 31) * 8] = d;
      }
    }
    __syncthreads();

    f4v s[4];
    #pragma unroll
    for (int lt = 0; lt < 4; ++lt) s[lt] = (f4v){0.f, 0.f, 0.f, 0.f};
    const ushort* xa_base = x_lds + (wave * 16 + l16) * 264 + quad * 8;
    #pragma unroll
    for (int cs = 0; cs < 8; ++cs) {
      s8v xa = *(const s8v*)(xa_base + cs * 32);
      #pragma unroll
      for (int lt = 0; lt < 4; ++lt)
        s[lt] = __builtin_amdgcn_mfma_f32_16x16x32_bf16(xa, kw[lt][cs], s[lt], 0, 0, 0);
    }

    const int nb = n0 + wave * 16 + quad * 4;
    if (p < 2) {
      ushort* outp = (p == 0) ? q_t : k_t;
      #pragma unroll
      for (int lt = 0; lt < 4; ++lt) {
        const int l = l0 + lt * 16 + l16;
        #pragma unroll
        for (int r = 0; r < 4; ++r)
          outp[(size_t)(b * N_ + nb + r) * C_ + l] = f2bf(s[lt][r] + bias_l[lt]);
      }
    } else {
      #pragma unroll
      for (int lt = 0; lt < 4; ++lt) {
        const int c_out = l0 + lt * 16 + l16;
        *(ushort4*)&v_bf[(size_t)(b * C_ + c_out) * N_ + nb] =
            make_ushort4(f2bf(s[lt][0] + bias_l[lt]), f2bf(s[lt][1] + bias_l[lt]),
                         f2bf(s[lt][2] + bias_l[lt]), f2bf(s[lt][3] + bias_l[lt]));
      }
    }
    __syncthreads();
  }
}

// ---------------------------------------------------------------------------
// flash8b R17 (resubmit — R0 bench was a container-infra failure, no data):
// R13 structure (barriers, operand sourcing, store paths all preserved)
// with the LDS *path* changed:
//   (a) q staged via global_load_lds (16B) into a LINEAR [64][32-chunk]
//       layout whose GLOBAL source address carries the XOR chunk-swizzle
//       (chunk ^= row&7, 16B granularity) — both-sides-or-neither rule.
//       Deletes 8 ds_write_b128 + reg round-trip + addr VALU per wave/iter.
//   (b) q_lds/p_lds XOR-swizzled: kills the 7.47M SQ_LDS_BANK_CONFLICT
//       cycles (~12%/CU) the +8-pad layout left on ds_read_b128.
//   (c) s_setprio(1) around MFMA clusters (T5): 2 desynced blocks/CU +
//       VALU-heavy softmax phase = wave role diversity to arbitrate.
// LDS 43008 -> 40960 B. Values and MFMA order identical to R13.
// grid (64, 2, 4) = (tj-blocks, i-segments, batch), block 256 (4 waves).
// ---------------------------------------------------------------------------
__global__ __launch_bounds__(256, 2) void flash8b(
    const ushort* __restrict__ q_t, const ushort* __restrict__ k_t,
    const ushort* __restrict__ v_bf, ushort* __restrict__ res0,
    ushort* __restrict__ res1, float* __restrict__ den)
{
  const int tid  = threadIdx.x;
  const int lane = tid & 63;
  const int wave = tid >> 6;
  const int l16  = lane & 15;
  const int quad = lane >> 4;
  const int jw    = blockIdx.x * 64;         // block tj base
  const int seg   = blockIdx.y;
  const int ibase = seg * 2048;              // i-segment base
  const int b     = blockIdx.z;

  const int wqk_j = wave & 1;                // QK: tj-pair (tj = wqk_j*32 + jt*16)
  const int wqk_i = wave >> 1;               // QK: i-pair  (i_loc = (wqk_i*2+itile)*16)

  // q_lds: [64 i][32 chunks x 8 ushort], chunk ^= (row&7). No pad.
  __shared__ __align__(16) ushort q_lds[64 * 256];   // reused by epilogue
  // p_lds: [64 tj][8 chunks x 8 ushort], chunk ^= (row&7). No pad.
  __shared__ __align__(16) ushort p_lds[64 * 64];

  // K fragments: wave's 32 tj x 256 c, resident whole kernel (64 VGPR)
  s8v kf[2][8];
  #pragma unroll
  for (int jt = 0; jt < 2; ++jt) {
    const ushort* kp = k_t + (size_t)(b * N_ + jw + wqk_j * 32 + jt * 16 + l16) * C_ + quad * 8;
    #pragma unroll
    for (int cs = 0; cs < 8; ++cs) kf[jt][cs] = *(const s8v*)(kp + cs * 32);
  }

  f4v acc[4][4];   // [m: c-tile][t: tj-tile]; c = wave*64+m*16+quad*4+r, tj = jw+t*16+l16
  #pragma unroll
  for (int m = 0; m < 4; ++m)
    #pragma unroll
    for (int t = 0; t < 4; ++t) acc[m][t] = (f4v){0.f, 0.f, 0.f, 0.f};
  float dacc0 = 0.f, dacc1 = 0.f;

  const ushort* vbase0 = v_bf + (size_t)(b * C_ + wave * 64 + l16) * N_ + quad * 8;

  for (int it = 0; it < 32; ++it) {
    const int i0 = ibase + it * 64;

    // stage q-chunk [64 i][256 c] -> LDS via global_load_lds, source-swizzled.
    // LDS chunk P = k*256 + wave*64 + lane holds global (row = P>>5,
    // colchunk = (lane&31) ^ (row&7)) -- the involution the reads undo.
    {
      const ushort* qseg = q_t + ((size_t)(b * N_) + i0) * C_;
      const int plo = lane & 31;
      #pragma unroll
      for (int k = 0; k < 8; ++k) {
        const int row = k * 8 + wave * 2 + (lane >> 5);
        const ushort* src = qseg + row * 256 + ((plo ^ (row & 7)) << 3);
        gload_lds16(src, &q_lds[k * 2048 + wave * 512]);
      }
    }

    // v A-frags: issue now, consumed after P-barrier
    s8v av[4][2];
    #pragma unroll
    for (int m = 0; m < 4; ++m)
      #pragma unroll
      for (int ks = 0; ks < 2; ++ks)
        av[m][ks] = *(const s8v*)(vbase0 + (size_t)(m * 16) * N_ + i0 + ks * 32);

    __syncthreads();   // q ready (vmcnt drained by barrier)

    // QK: 2 i-tiles x 2 tj-tiles, A from LDS (swizzled read), B from registers
    #pragma unroll
    for (int itile = 0; itile < 2; ++itile) {
      const int i_loc = (wqk_i * 2 + itile) * 16;
      f4v s0 = (f4v){0.f, 0.f, 0.f, 0.f};
      f4v s1 = (f4v){0.f, 0.f, 0.f, 0.f};
      const int qrow = i_loc + l16;
      const ushort* qa_row = q_lds + qrow * 256;
      const int qsw = qrow & 7;
      __builtin_amdgcn_s_setprio(1);
      #pragma unroll
      for (int cs = 0; cs < 8; ++cs) {
        s8v qa = *(const s8v*)(qa_row + (((quad + 4 * cs) ^ qsw) << 3));
        s0 = __builtin_amdgcn_mfma_f32_16x16x32_bf16(qa, kf[0][cs], s0, 0, 0, 0);
        s1 = __builtin_amdgcn_mfma_f32_16x16x32_bf16(qa, kf[1][cs], s1, 0, 0, 0);
      }
      __builtin_amdgcn_s_setprio(0);
      {
        float e0 = __expf(s0[0] * SCALE), e1 = __expf(s0[1] * SCALE);
        float e2 = __expf(s0[2] * SCALE), e3 = __expf(s0[3] * SCALE);
        dacc0 += (e0 + e1) + (e2 + e3);
        const int row = wqk_j * 32 + l16;
        const int col = i_loc + quad * 4;
        *(ushort4*)&p_lds[row * 64 + ((((col >> 3) ^ (row & 7)) << 3) | (col & 7))] =
            make_ushort4(f2bf(e0), f2bf(e1), f2bf(e2), f2bf(e3));
      }
      {
        float e0 = __expf(s1[0] * SCALE), e1 = __expf(s1[1] * SCALE);
        float e2 = __expf(s1[2] * SCALE), e3 = __expf(s1[3] * SCALE);
        dacc1 += (e0 + e1) + (e2 + e3);
        const int row = wqk_j * 32 + 16 + l16;
        const int col = i_loc + quad * 4;
        *(ushort4*)&p_lds[row * 64 + ((((col >> 3) ^ (row & 7)) << 3) | (col & 7))] =
            make_ushort4(f2bf(e0), f2bf(e1), f2bf(e2), f2bf(e3));
      }
    }

    __syncthreads();   // P ready (also drains av loads)

    // PV: 4 c-tiles x 4 tj-tiles, A = av regs, B from p_lds (swizzled read)
    #pragma unroll
    for (int ks = 0; ks < 2; ++ks) {
      s8v pb[4];
      #pragma unroll
      for (int t = 0; t < 4; ++t) {
        const int row = t * 16 + l16;
        const int col = ks * 32 + quad * 8;
        pb[t] = *(const s8v*)&p_lds[row * 64 + (((col >> 3) ^ (row & 7)) << 3)];
      }
      __builtin_amdgcn_s_setprio(1);
      #pragma unroll
      for (int m = 0; m < 4; ++m)
        #pragma unroll
        for (int t = 0; t < 4; ++t)
          acc[m][t] = __builtin_amdgcn_mfma_f32_16x16x32_bf16(av[m][ks], pb[t], acc[m][t], 0, 0, 0);
      __builtin_amdgcn_s_setprio(0);
    }
  }

  // ---- denom: lanes l, l^16, l^32 share tj; butterfly then atomic ----
  dacc0 += __shfl_xor(dacc0, 16);  dacc0 += __shfl_xor(dacc0, 32);
  dacc1 += __shfl_xor(dacc1, 16);  dacc1 += __shfl_xor(dacc1, 32);
  if (lane < 16) {
    atomicAdd(&den[b * N_ + jw + wqk_j * 32 + lane], dacc0);
    atomicAdd(&den[b * N_ + jw + wqk_j * 32 + 16 + lane], dacc1);
  }

  // ---- epilogue: assemble [64 j][256 c] tile in q_lds (swizzled), store ----
  #pragma unroll
  for (int m = 0; m < 4; ++m) {
    const int c0 = wave * 64 + m * 16 + quad * 4;
    #pragma unroll
    for (int t = 0; t < 4; ++t) {
      const int row = t * 16 + l16;
      *(ushort4*)&q_lds[row * 256 + ((((c0 >> 3) ^ (row & 7)) << 3) | (c0 & 7))] =
          make_ushort4(f2bf(acc[m][t][0]), f2bf(acc[m][t][1]),
                       f2bf(acc[m][t][2]), f2bf(acc[m][t][3]));
    }
  }
  __syncthreads();   // tile assembled
  {
    ushort* rp = (seg ? res1 : res0) + (size_t)(b * N_ + jw) * C_;
    #pragma unroll
    for (int k = 0; k < 8; ++k) {
      int c = tid + k * 256;                 // 2048 16B-chunks
      int row = c >> 5, ch = c & 31;
      uint4 d = *(const uint4*)&q_lds[row * 256 + ((ch ^ (row & 7)) << 3)];
      *(uint4*)&rp[(size_t)row * C_ + ch * 8] = d;
    }
  }
}

// ---------------------------------------------------------------------------
// out_mfma: out[b][co][n] = bo[co] + Wo[co][:]·(res0+res1)[b][n][:] / den[b][n]
// (R13-exact). grid (16, 4, 4), block 256.
// ---------------------------------------------------------------------------
__global__ __launch_bounds__(256, 2) void out_mfma(
    const ushort* __restrict__ res0, const ushort* __restrict__ res1,
    const float* __restrict__ Wo, const float* __restrict__ bo,
    const float* __restrict__ den, float* __restrict__ out)
{
  const int b    = blockIdx.z;
  const int co0  = blockIdx.y * 64;
  const int nseg = blockIdx.x * 256;

  const int tid  = threadIdx.x;
  const int lane = tid & 63;
  const int wave = tid >> 6;
  const int l16  = lane & 15;
  const int quad = lane >> 4;

  __shared__ __align__(16) ushort w_lds[64 * 264];
  __shared__ __align__(16) ushort r_lds[2][64 * 264];

  for (int g = tid; g < 4096; g += 256) {
    int row = g >> 6, col4 = (g & 63) * 4;
    float4 wv = *(const float4*)(Wo + (size_t)(co0 + row) * 256 + col4);
    *(ushort4*)&w_lds[row * 264 + col4] =
        make_ushort4(f2bf(wv.x), f2bf(wv.y), f2bf(wv.z), f2bf(wv.w));
  }
  __syncthreads();

  s8v kw[4][8];
  #pragma unroll
  for (int lt = 0; lt < 4; ++lt)
    #pragma unroll
    for (int cs = 0; cs < 8; ++cs)
      kw[lt][cs] = *(const s8v*)&w_lds[(lt * 16 + l16) * 264 + quad * 8 + cs * 32];

  float bias_l[4];
  #pragma unroll
  for (int lt = 0; lt < 4; ++lt) bias_l[lt] = bo[co0 + lt * 16 + l16];

  for (int it = 0; it < 4; ++it) {
    const int n0 = nseg + it * 64;
    {
      const ushort* r0 = res0 + (size_t)(b * N_ + n0) * C_;
      const ushort* r1 = res1 + (size_t)(b * N_ + n0) * C_;
      #pragma unroll
      for (int k = 0; k < 8; ++k) {
        int c = tid + k * 256;
        uint4 d0 = *(const uint4*)(r0 + (size_t)c * 8);
        uint4 d1 = *(const uint4*)(r1 + (size_t)c * 8);
        *(uint4*)&r_lds[0][(c >> 5) * 264 + (c & 31) * 8] = d0;
        *(uint4*)&r_lds[1][(c >> 5) * 264 + (c & 31) * 8] = d1;
      }
    }
    __syncthreads();

    f4v s[4];
    #pragma unroll
    for (int lt = 0; lt < 4; ++lt) s[lt] = (f4v){0.f, 0.f, 0.f, 0.f};
    #pragma unroll
    for (int buf = 0; buf < 2; ++buf) {
      const ushort* ra_base = r_lds[buf] + (wave * 16 + l16) * 264 + quad * 8;
      #pragma unroll
      for (int cs = 0; cs < 8; ++cs) {
        s8v ra = *(const s8v*)(ra_base + cs * 32);
        #pragma unroll
        for (int lt = 0; lt < 4; ++lt)
          s[lt] = __builtin_amdgcn_mfma_f32_16x16x32_bf16(ra, kw[lt][cs], s[lt], 0, 0, 0);
      }
    }

    const int nb = n0 + wave * 16 + quad * 4;
    float4 dv = *(const float4*)(den + (size_t)b * N_ + nb);
    const float di0 = 1.0f / dv.x, di1 = 1.0f / dv.y, di2 = 1.0f / dv.z, di3 = 1.0f / dv.w;
    #pragma unroll
    for (int lt = 0; lt < 4; ++lt) {
      const int co = co0 + lt * 16 + l16;
      *(float4*)&out[(size_t)(b * C_ + co) * N_ + nb] =
          make_float4(s[lt][0] * di0 + bias_l[lt], s[lt][1] * di1 + bias_l[lt],
                      s[lt][2] * di2 + bias_l[lt], s[lt][3] * di3 + bias_l[lt]);
    }
    __syncthreads();
  }
}

// ---------------------------------------------------------------------------
extern "C" void kernel_launch(void* const* d_in, const int* in_sizes, int n_in,
                              void* d_out, int out_size, void* d_ws, size_t ws_size,
                              hipStream_t stream)
{
  const float* x  = (const float*)d_in[0];
  const float* Wq = (const float*)d_in[1];
  const float* bq = (const float*)d_in[2];
  const float* Wk = (const float*)d_in[3];
  const float* bk = (const float*)d_in[4];
  const float* Wv = (const float*)d_in[5];
  const float* bv = (const float*)d_in[6];
  const float* Wo = (const float*)d_in[7];
  const float* bo = (const float*)d_in[8];
  float* out = (float*)d_out;

  // workspace layout (~48.1 MB):
  //   q_t   [B][N][L] bf16 : 8 MB   (transposed)
  //   k_t   [B][N][L] bf16 : 8 MB   (transposed)
  //   v_bf  [B][L][N] bf16 : 8 MB   (natural)
  //   res0  [B][N][L] bf16 : 8 MB   (numerator partial, i-segment 0)
  //   res1  [B][N][L] bf16 : 8 MB   (numerator partial, i-segment 1)
  //   den   [B][N]    fp32 : 64 KB  (softmax denominators; zeroed in xpose_cast)
  //   x_t   [B][N][C] bf16 : 8 MB   (transposed+cast input)
  char* ws = (char*)d_ws;
  ushort* q_t  = (ushort*)(ws);
  ushort* k_t  = (ushort*)(ws + (size_t)8  * 1024 * 1024);
  ushort* v_bf = (ushort*)(ws + (size_t)16 * 1024 * 1024);
  ushort* res0 = (ushort*)(ws + (size_t)24 * 1024 * 1024);
  ushort* res1 = (ushort*)(ws + (size_t)32 * 1024 * 1024);
  float*  den  = (float*) (ws + (size_t)40 * 1024 * 1024);
  ushort* x_t  = (ushort*)(ws + (size_t)40 * 1024 * 1024 + 65536);

  xpose_cast<<<dim3(64, 4, 4), dim3(256), 0, stream>>>(x, x_t, den);
  qkv_mfma <<<dim3(8, 4, 12),  dim3(256), 0, stream>>>(x_t, Wq, bq, Wk, bk, Wv, bv, q_t, k_t, v_bf);
  flash8b  <<<dim3(64, 2, 4),  dim3(256), 0, stream>>>(q_t, k_t, v_bf, res0, res1, den);
  out_mfma <<<dim3(16, 4, 4),  dim3(256), 0, stream>>>(res0, res1, Wo, bo, den, out);
}

// Round 3
// 205.080 us; speedup vs baseline: 1.0149x; 1.0149x over previous
//
#include <hip/hip_runtime.h>

#define B_  4
#define C_  256     // C_IN == LATENT == 256
#define N_  4096    // H*W
#define SCALE 0.0625f   // 1/sqrt(256)

typedef short s8v __attribute__((ext_vector_type(8)));
typedef float f4v __attribute__((ext_vector_type(4)));

// round-to-nearest-even fp32 -> bf16 (values are finite; no NaN handling needed)
static __device__ __forceinline__ ushort f2bf(float f) {
  union { float f; uint u; } v; v.f = f;
  return (ushort)((v.u + 0x7FFFu + ((v.u >> 16) & 1u)) >> 16);
}

// async global->LDS 16B: dest is wave-uniform base + lane*16 (linear).
static __device__ __forceinline__ void gload_lds16(const ushort* g, ushort* l) {
  __builtin_amdgcn_global_load_lds(
      (const __attribute__((address_space(1))) void*)g,
      (__attribute__((address_space(3))) void*)l, 16, 0, 0);
}

// ---------------------------------------------------------------------------
// xpose_cast: x [b][c][n] fp32 -> x_t [b][n][c] bf16 + fused den zeroing.
// (R13-exact). grid (64, 4, 4).
// ---------------------------------------------------------------------------
__global__ __launch_bounds__(256) void xpose_cast(
    const float* __restrict__ x, ushort* __restrict__ x_t,
    float* __restrict__ den)
{
  const int b  = blockIdx.z;
  const int c0 = blockIdx.y * 64;
  const int n0 = blockIdx.x * 64;
  __shared__ float t[64][65];

  if (blockIdx.y == 0 && threadIdx.x < 64)
    den[b * N_ + n0 + threadIdx.x] = 0.f;

  const int tc = threadIdx.x >> 4;
  const int tn = (threadIdx.x & 15) * 4;
  #pragma unroll
  for (int cc = 0; cc < 64; cc += 16) {
    float4 v = *(const float4*)(x + (size_t)(b * C_ + c0 + cc + tc) * N_ + n0 + tn);
    t[cc + tc][tn + 0] = v.x;
    t[cc + tc][tn + 1] = v.y;
    t[cc + tc][tn + 2] = v.z;
    t[cc + tc][tn + 3] = v.w;
  }
  __syncthreads();

  const int on = threadIdx.x >> 2;
  const int oc = (threadIdx.x & 3) * 16;
  union { ushort us[16]; uint4 q[2]; } o;
  #pragma unroll
  for (int i = 0; i < 16; ++i) o.us[i] = f2bf(t[oc + i][on]);
  ushort* dst = x_t + (size_t)(b * N_ + n0 + on) * C_ + c0 + oc;
  *(uint4*)dst       = o.q[0];
  *(uint4*)(dst + 8) = o.q[1];
}

// ---------------------------------------------------------------------------
// qkv_mfma: bf16 MFMA projection (R13-exact). grid (8, 4, 12), block 256.
// ---------------------------------------------------------------------------
__global__ __launch_bounds__(256, 2) void qkv_mfma(
    const ushort* __restrict__ x_t,
    const float* __restrict__ Wq, const float* __restrict__ bq,
    const float* __restrict__ Wk, const float* __restrict__ bk,
    const float* __restrict__ Wv, const float* __restrict__ bv,
    ushort* __restrict__ q_t, ushort* __restrict__ k_t, ushort* __restrict__ v_bf)
{
  const int p = blockIdx.z >> 2;
  const int b = blockIdx.z & 3;
  const float* W  = (p == 0) ? Wq : (p == 1) ? Wk : Wv;
  const float* bi = (p == 0) ? bq : (p == 1) ? bk : bv;
  const int l0    = blockIdx.y * 64;
  const int nseg  = blockIdx.x * 512;

  const int tid  = threadIdx.x;
  const int lane = tid & 63;
  const int wave = tid >> 6;
  const int l16  = lane & 15;
  const int quad = lane >> 4;

  __shared__ __align__(16) ushort w_lds[64 * 264];
  __shared__ __align__(16) ushort x_lds[64 * 264];

  for (int g = tid; g < 4096; g += 256) {
    int row = g >> 6, col4 = (g & 63) * 4;
    float4 wv = *(const float4*)(W + (size_t)(l0 + row) * 256 + col4);
    *(ushort4*)&w_lds[row * 264 + col4] =
        make_ushort4(f2bf(wv.x), f2bf(wv.y), f2bf(wv.z), f2bf(wv.w));
  }
  __syncthreads();

  s8v kw[4][8];
  #pragma unroll
  for (int lt = 0; lt < 4; ++lt)
    #pragma unroll
    for (int cs = 0; cs < 8; ++cs)
      kw[lt][cs] = *(const s8v*)&w_lds[(lt * 16 + l16) * 264 + quad * 8 + cs * 32];

  float bias_l[4];
  #pragma unroll
  for (int lt = 0; lt < 4; ++lt) bias_l[lt] = bi[l0 + lt * 16 + l16];

  for (int it = 0; it < 8; ++it) {
    const int n0 = nseg + it * 64;
    {
      const ushort* xseg = x_t + (size_t)(b * N_ + n0) * C_;
      #pragma unroll
      for (int k = 0; k < 8; ++k) {
        int c = tid + k * 256;
        uint4 d = *(const uint4*)(xseg + (size_t)c * 8);
        *(uint4*)&x_lds[(c >> 5) * 264 + (c & 31) * 8] = d;
      }
    }
    __syncthreads();

    f4v s[4];
    #pragma unroll
    for (int lt = 0; lt < 4; ++lt) s[lt] = (f4v){0.f, 0.f, 0.f, 0.f};
    const ushort* xa_base = x_lds + (wave * 16 + l16) * 264 + quad * 8;
    #pragma unroll
    for (int cs = 0; cs < 8; ++cs) {
      s8v xa = *(const s8v*)(xa_base + cs * 32);
      #pragma unroll
      for (int lt = 0; lt < 4; ++lt)
        s[lt] = __builtin_amdgcn_mfma_f32_16x16x32_bf16(xa, kw[lt][cs], s[lt], 0, 0, 0);
    }

    const int nb = n0 + wave * 16 + quad * 4;
    if (p < 2) {
      ushort* outp = (p == 0) ? q_t : k_t;
      #pragma unroll
      for (int lt = 0; lt < 4; ++lt) {
        const int l = l0 + lt * 16 + l16;
        #pragma unroll
        for (int r = 0; r < 4; ++r)
          outp[(size_t)(b * N_ + nb + r) * C_ + l] = f2bf(s[lt][r] + bias_l[lt]);
      }
    } else {
      #pragma unroll
      for (int lt = 0; lt < 4; ++lt) {
        const int c_out = l0 + lt * 16 + l16;
        *(ushort4*)&v_bf[(size_t)(b * C_ + c_out) * N_ + nb] =
            make_ushort4(f2bf(s[lt][0] + bias_l[lt]), f2bf(s[lt][1] + bias_l[lt]),
                         f2bf(s[lt][2] + bias_l[lt]), f2bf(s[lt][3] + bias_l[lt]));
      }
    }
    __syncthreads();
  }
}

// ---------------------------------------------------------------------------
// flash8b R18: break the 2-phase drain wall (R17 post-mortem: 674 TF = the
// m230/m233 2-phase structural ceiling; T2 swizzle cut conflicts 28% but
// timing was null -> conflicts not on critical path, the vmcnt(0) drain at
// each __syncthreads is).
// Changes vs R17 (QK/PV math, swizzles, epilogue identical):
//   (a) q_lds double-buffered (2x32KB); iteration t prefetches t+1's q-stage.
//   (b) raw s_barrier + counted s_waitcnt vmcnt(16): drains exactly iter-t's
//       8 gload_lds (oldest), leaves av(t) [8] + q(t+1) [8] in flight across
//       both barriers. av issued BEFORE stage(t+1) so the compiler's own
//       pre-PV wait is vmcnt(8), keeping q(t+1) airborne. Loads never drain
//       to 0 in the main loop (T4).
//   (c) barrier 2 preceded only by lgkmcnt(0) (p_lds write visibility).
//   (d) last iter stages a dummy (clamped index) so counts stay uniform;
//       post-loop __syncthreads drains it before epilogue reuses q_lds[0].
//   sched_barrier(0) fences pin issue order (rule #18) so counts are exact.
// LDS 72KB (2 blocks/CU preserved: 144KB < 160KB).
// grid (64, 2, 4) = (tj-blocks, i-segments, batch), block 256 (4 waves).
// ---------------------------------------------------------------------------
__global__ __launch_bounds__(256, 2) void flash8b(
    const ushort* __restrict__ q_t, const ushort* __restrict__ k_t,
    const ushort* __restrict__ v_bf, ushort* __restrict__ res0,
    ushort* __restrict__ res1, float* __restrict__ den)
{
  const int tid  = threadIdx.x;
  const int lane = tid & 63;
  const int wave = tid >> 6;
  const int l16  = lane & 15;
  const int quad = lane >> 4;
  const int jw    = blockIdx.x * 64;         // block tj base
  const int seg   = blockIdx.y;
  const int ibase = seg * 2048;              // i-segment base
  const int b     = blockIdx.z;

  const int wqk_j = wave & 1;                // QK: tj-pair (tj = wqk_j*32 + jt*16)
  const int wqk_i = wave >> 1;               // QK: i-pair  (i_loc = (wqk_i*2+itile)*16)

  // q_lds: 2 buffers of [64 i][32 chunks x 8 ushort], chunk ^= (row&7).
  __shared__ __align__(16) ushort q_lds[2][64 * 256];  // [0] reused by epilogue
  // p_lds: [64 tj][8 chunks x 8 ushort], chunk ^= (row&7). No pad.
  __shared__ __align__(16) ushort p_lds[64 * 64];

  const ushort* qseg_b = q_t + (size_t)(b * N_) * C_;
  const int plo = lane & 31;

  // K fragments: wave's 32 tj x 256 c, resident whole kernel (64 VGPR)
  s8v kf[2][8];
  #pragma unroll
  for (int jt = 0; jt < 2; ++jt) {
    const ushort* kp = k_t + (size_t)(b * N_ + jw + wqk_j * 32 + jt * 16 + l16) * C_ + quad * 8;
    #pragma unroll
    for (int cs = 0; cs < 8; ++cs) kf[jt][cs] = *(const s8v*)(kp + cs * 32);
  }

  // prologue: stage q(0) into buffer 0 (source-swizzled, as R17)
  {
    const ushort* qseg = qseg_b + (size_t)ibase * C_;
    #pragma unroll
    for (int k = 0; k < 8; ++k) {
      const int row = k * 8 + wave * 2 + (lane >> 5);
      gload_lds16(qseg + row * 256 + ((plo ^ (row & 7)) << 3),
                  &q_lds[0][k * 2048 + wave * 512]);
    }
  }

  f4v acc[4][4];   // [m: c-tile][t: tj-tile]; c = wave*64+m*16+quad*4+r, tj = jw+t*16+l16
  #pragma unroll
  for (int m = 0; m < 4; ++m)
    #pragma unroll
    for (int t = 0; t < 4; ++t) acc[m][t] = (f4v){0.f, 0.f, 0.f, 0.f};
  float dacc0 = 0.f, dacc1 = 0.f;

  const ushort* vbase0 = v_bf + (size_t)(b * C_ + wave * 64 + l16) * N_ + quad * 8;

  #pragma unroll 1
  for (int it = 0; it < 32; ++it) {
    const int cur = it & 1;
    const int i0 = ibase + it * 64;
    const int inext = (it < 31) ? (it + 1) : 31;   // dummy re-stage keeps counts uniform

    // v A-frags for THIS iter: issued first (oldest group) so the compiler's
    // pre-PV wait leaves the newer q(t+1) staging in flight.
    s8v av[4][2];
    #pragma unroll
    for (int m = 0; m < 4; ++m)
      #pragma unroll
      for (int ks = 0; ks < 2; ++ks)
        av[m][ks] = *(const s8v*)(vbase0 + (size_t)(m * 16) * N_ + i0 + ks * 32);

    __builtin_amdgcn_sched_barrier(0);

    // prefetch q(t+1) into the other buffer (8 gload_lds, newest group)
    {
      const ushort* qseg = qseg_b + (size_t)(ibase + inext * 64) * C_;
      ushort* dstb = &q_lds[cur ^ 1][0];
      #pragma unroll
      for (int k = 0; k < 8; ++k) {
        const int row = k * 8 + wave * 2 + (lane >> 5);
        gload_lds16(qseg + row * 256 + ((plo ^ (row & 7)) << 3),
                    dstb + k * 2048 + wave * 512);
      }
    }

    __builtin_amdgcn_sched_barrier(0);
    // drain exactly the oldest 8 vmem ops = q(t)'s staging; av(t) [8] and
    // q(t+1) [8] stay in flight (vmcnt retires oldest-first, m135).
    asm volatile("s_waitcnt vmcnt(16)" ::: "memory");
    __builtin_amdgcn_sched_barrier(0);
    __builtin_amdgcn_s_barrier();              // q[cur] ready for all waves
    __builtin_amdgcn_sched_barrier(0);

    // QK: 2 i-tiles x 2 tj-tiles, A from q_lds[cur] (swizzled), B from regs
    #pragma unroll
    for (int itile = 0; itile < 2; ++itile) {
      const int i_loc = (wqk_i * 2 + itile) * 16;
      f4v s0 = (f4v){0.f, 0.f, 0.f, 0.f};
      f4v s1 = (f4v){0.f, 0.f, 0.f, 0.f};
      const int qrow = i_loc + l16;
      const ushort* qa_row = &q_lds[cur][0] + qrow * 256;
      const int qsw = qrow & 7;
      __builtin_amdgcn_s_setprio(1);
      #pragma unroll
      for (int cs = 0; cs < 8; ++cs) {
        s8v qa = *(const s8v*)(qa_row + (((quad + 4 * cs) ^ qsw) << 3));
        s0 = __builtin_amdgcn_mfma_f32_16x16x32_bf16(qa, kf[0][cs], s0, 0, 0, 0);
        s1 = __builtin_amdgcn_mfma_f32_16x16x32_bf16(qa, kf[1][cs], s1, 0, 0, 0);
      }
      __builtin_amdgcn_s_setprio(0);
      {
        float e0 = __expf(s0[0] * SCALE), e1 = __expf(s0[1] * SCALE);
        float e2 = __expf(s0[2] * SCALE), e3 = __expf(s0[3] * SCALE);
        dacc0 += (e0 + e1) + (e2 + e3);
        const int row = wqk_j * 32 + l16;
        const int col = i_loc + quad * 4;
        *(ushort4*)&p_lds[row * 64 + ((((col >> 3) ^ (row & 7)) << 3) | (col & 7))] =
            make_ushort4(f2bf(e0), f2bf(e1), f2bf(e2), f2bf(e3));
      }
      {
        float e0 = __expf(s1[0] * SCALE), e1 = __expf(s1[1] * SCALE);
        float e2 = __expf(s1[2] * SCALE), e3 = __expf(s1[3] * SCALE);
        dacc1 += (e0 + e1) + (e2 + e3);
        const int row = wqk_j * 32 + 16 + l16;
        const int col = i_loc + quad * 4;
        *(ushort4*)&p_lds[row * 64 + ((((col >> 3) ^ (row & 7)) << 3) | (col & 7))] =
            make_ushort4(f2bf(e0), f2bf(e1), f2bf(e2), f2bf(e3));
      }
    }

    __builtin_amdgcn_sched_barrier(0);
    // p_lds writes must be visible before other waves read; DS-only drain —
    // the in-flight vmem (av(t), q(t+1)) is deliberately NOT drained.
    asm volatile("s_waitcnt lgkmcnt(0)" ::: "memory");
    __builtin_amdgcn_sched_barrier(0);
    __builtin_amdgcn_s_barrier();              // P ready
    __builtin_amdgcn_sched_barrier(0);

    // PV: 4 c-tiles x 4 tj-tiles, A = av regs (compiler-inserted vmcnt(8)
    // waits av only), B from p_lds (swizzled read)
    #pragma unroll
    for (int ks = 0; ks < 2; ++ks) {
      s8v pb[4];
      #pragma unroll
      for (int t = 0; t < 4; ++t) {
        const int row = t * 16 + l16;
        const int col = ks * 32 + quad * 8;
        pb[t] = *(const s8v*)&p_lds[row * 64 + (((col >> 3) ^ (row & 7)) << 3)];
      }
      __builtin_amdgcn_s_setprio(1);
      #pragma unroll
      for (int m = 0; m < 4; ++m)
        #pragma unroll
        for (int t = 0; t < 4; ++t)
          acc[m][t] = __builtin_amdgcn_mfma_f32_16x16x32_bf16(av[m][ks], pb[t], acc[m][t], 0, 0, 0);
      __builtin_amdgcn_s_setprio(0);
    }
  }

  // full drain (dummy stage + anything outstanding) before epilogue reuses
  // q_lds[0] — __syncthreads emits vmcnt(0) lgkmcnt(0) + barrier.
  __syncthreads();

  // ---- denom: lanes l, l^16, l^32 share tj; butterfly then atomic ----
  dacc0 += __shfl_xor(dacc0, 16);  dacc0 += __shfl_xor(dacc0, 32);
  dacc1 += __shfl_xor(dacc1, 16);  dacc1 += __shfl_xor(dacc1, 32);
  if (lane < 16) {
    atomicAdd(&den[b * N_ + jw + wqk_j * 32 + lane], dacc0);
    atomicAdd(&den[b * N_ + jw + wqk_j * 32 + 16 + lane], dacc1);
  }

  // ---- epilogue: assemble [64 j][256 c] tile in q_lds[0] (swizzled), store ----
  #pragma unroll
  for (int m = 0; m < 4; ++m) {
    const int c0 = wave * 64 + m * 16 + quad * 4;
    #pragma unroll
    for (int t = 0; t < 4; ++t) {
      const int row = t * 16 + l16;
      *(ushort4*)&q_lds[0][row * 256 + ((((c0 >> 3) ^ (row & 7)) << 3) | (c0 & 7))] =
          make_ushort4(f2bf(acc[m][t][0]), f2bf(acc[m][t][1]),
                       f2bf(acc[m][t][2]), f2bf(acc[m][t][3]));
    }
  }
  __syncthreads();   // tile assembled
  {
    ushort* rp = (seg ? res1 : res0) + (size_t)(b * N_ + jw) * C_;
    #pragma unroll
    for (int k = 0; k < 8; ++k) {
      int c = tid + k * 256;                 // 2048 16B-chunks
      int row = c >> 5, ch = c & 31;
      uint4 d = *(const uint4*)&q_lds[0][row * 256 + ((ch ^ (row & 7)) << 3)];
      *(uint4*)&rp[(size_t)row * C_ + ch * 8] = d;
    }
  }
}

// ---------------------------------------------------------------------------
// out_mfma: out[b][co][n] = bo[co] + Wo[co][:]·(res0+res1)[b][n][:] / den[b][n]
// (R13-exact). grid (16, 4, 4), block 256.
// ---------------------------------------------------------------------------
__global__ __launch_bounds__(256, 2) void out_mfma(
    const ushort* __restrict__ res0, const ushort* __restrict__ res1,
    const float* __restrict__ Wo, const float* __restrict__ bo,
    const float* __restrict__ den, float* __restrict__ out)
{
  const int b    = blockIdx.z;
  const int co0  = blockIdx.y * 64;
  const int nseg = blockIdx.x * 256;

  const int tid  = threadIdx.x;
  const int lane = tid & 63;
  const int wave = tid >> 6;
  const int l16  = lane & 15;
  const int quad = lane >> 4;

  __shared__ __align__(16) ushort w_lds[64 * 264];
  __shared__ __align__(16) ushort r_lds[2][64 * 264];

  for (int g = tid; g < 4096; g += 256) {
    int row = g >> 6, col4 = (g & 63) * 4;
    float4 wv = *(const float4*)(Wo + (size_t)(co0 + row) * 256 + col4);
    *(ushort4*)&w_lds[row * 264 + col4] =
        make_ushort4(f2bf(wv.x), f2bf(wv.y), f2bf(wv.z), f2bf(wv.w));
  }
  __syncthreads();

  s8v kw[4][8];
  #pragma unroll
  for (int lt = 0; lt < 4; ++lt)
    #pragma unroll
    for (int cs = 0; cs < 8; ++cs)
      kw[lt][cs] = *(const s8v*)&w_lds[(lt * 16 + l16) * 264 + quad * 8 + cs * 32];

  float bias_l[4];
  #pragma unroll
  for (int lt = 0; lt < 4; ++lt) bias_l[lt] = bo[co0 + lt * 16 + l16];

  for (int it = 0; it < 4; ++it) {
    const int n0 = nseg + it * 64;
    {
      const ushort* r0 = res0 + (size_t)(b * N_ + n0) * C_;
      const ushort* r1 = res1 + (size_t)(b * N_ + n0) * C_;
      #pragma unroll
      for (int k = 0; k < 8; ++k) {
        int c = tid + k * 256;
        uint4 d0 = *(const uint4*)(r0 + (size_t)c * 8);
        uint4 d1 = *(const uint4*)(r1 + (size_t)c * 8);
        *(uint4*)&r_lds[0][(c >> 5) * 264 + (c & 31) * 8] = d0;
        *(uint4*)&r_lds[1][(c >> 5) * 264 + (c & 31) * 8] = d1;
      }
    }
    __syncthreads();

    f4v s[4];
    #pragma unroll
    for (int lt = 0; lt < 4; ++lt) s[lt] = (f4v){0.f, 0.f, 0.f, 0.f};
    #pragma unroll
    for (int buf = 0; buf < 2; ++buf) {
      const ushort* ra_base = r_lds[buf] + (wave * 16 + l16) * 264 + quad * 8;
      #pragma unroll
      for (int cs = 0; cs < 8; ++cs) {
        s8v ra = *(const s8v*)(ra_base + cs * 32);
        #pragma unroll
        for (int lt = 0; lt < 4; ++lt)
          s[lt] = __builtin_amdgcn_mfma_f32_16x16x32_bf16(ra, kw[lt][cs], s[lt], 0, 0, 0);
      }
    }

    const int nb = n0 + wave * 16 + quad * 4;
    float4 dv = *(const float4*)(den + (size_t)b * N_ + nb);
    const float di0 = 1.0f / dv.x, di1 = 1.0f / dv.y, di2 = 1.0f / dv.z, di3 = 1.0f / dv.w;
    #pragma unroll
    for (int lt = 0; lt < 4; ++lt) {
      const int co = co0 + lt * 16 + l16;
      *(float4*)&out[(size_t)(b * C_ + co) * N_ + nb] =
          make_float4(s[lt][0] * di0 + bias_l[lt], s[lt][1] * di1 + bias_l[lt],
                      s[lt][2] * di2 + bias_l[lt], s[lt][3] * di3 + bias_l[lt]);
    }
    __syncthreads();
  }
}

// ---------------------------------------------------------------------------
extern "C" void kernel_launch(void* const* d_in, const int* in_sizes, int n_in,
                              void* d_out, int out_size, void* d_ws, size_t ws_size,
                              hipStream_t stream)
{
  const float* x  = (const float*)d_in[0];
  const float* Wq = (const float*)d_in[1];
  const float* bq = (const float*)d_in[2];
  const float* Wk = (const float*)d_in[3];
  const float* bk = (const float*)d_in[4];
  const float* Wv = (const float*)d_in[5];
  const float* bv = (const float*)d_in[6];
  const float* Wo = (const float*)d_in[7];
  const float* bo = (const float*)d_in[8];
  float* out = (float*)d_out;

  // workspace layout (~48.1 MB):
  //   q_t   [B][N][L] bf16 : 8 MB   (transposed)
  //   k_t   [B][N][L] bf16 : 8 MB   (transposed)
  //   v_bf  [B][L][N] bf16 : 8 MB   (natural)
  //   res0  [B][N][L] bf16 : 8 MB   (numerator partial, i-segment 0)
  //   res1  [B][N][L] bf16 : 8 MB   (numerator partial, i-segment 1)
  //   den   [B][N]    fp32 : 64 KB  (softmax denominators; zeroed in xpose_cast)
  //   x_t   [B][N][C] bf16 : 8 MB   (transposed+cast input)
  char* ws = (char*)d_ws;
  ushort* q_t  = (ushort*)(ws);
  ushort* k_t  = (ushort*)(ws + (size_t)8  * 1024 * 1024);
  ushort* v_bf = (ushort*)(ws + (size_t)16 * 1024 * 1024);
  ushort* res0 = (ushort*)(ws + (size_t)24 * 1024 * 1024);
  ushort* res1 = (ushort*)(ws + (size_t)32 * 1024 * 1024);
  float*  den  = (float*) (ws + (size_t)40 * 1024 * 1024);
  ushort* x_t  = (ushort*)(ws + (size_t)40 * 1024 * 1024 + 65536);

  xpose_cast<<<dim3(64, 4, 4), dim3(256), 0, stream>>>(x, x_t, den);
  qkv_mfma <<<dim3(8, 4, 12),  dim3(256), 0, stream>>>(x_t, Wq, bq, Wk, bk, Wv, bv, q_t, k_t, v_bf);
  flash8b  <<<dim3(64, 2, 4),  dim3(256), 0, stream>>>(q_t, k_t, v_bf, res0, res1, den);
  out_mfma <<<dim3(16, 4, 4),  dim3(256), 0, stream>>>(res0, res1, Wo, bo, den, out);
}